// Round 1
// baseline (407.625 us; speedup 1.0000x reference)
//
#include <hip/hip_runtime.h>

typedef __attribute__((ext_vector_type(4))) short bf16x4;
typedef __attribute__((ext_vector_type(8))) short bf16x8;
typedef __attribute__((ext_vector_type(16))) float f32x16;
typedef __attribute__((ext_vector_type(2))) float f32x2;
typedef __attribute__((ext_vector_type(4))) unsigned int u32x4;

__device__ __forceinline__ unsigned short f2bf(float f) {
    unsigned int u = __builtin_bit_cast(unsigned int, f);
    u += 0x7fffu + ((u >> 16) & 1u);   // RNE (inputs are finite normals)
    return (unsigned short)(u >> 16);
}

#define PA 196   // lds_a pitch in bf16 elems: 196*2B=392B -> 98 dwords, 98%32=2 -> conflict-free-ish

// GEMM: z_partial[b] = feats[:, Kslice(b)] @ W[Kslice(b), :]
// feats computed on the fly from x via Rtot (3x3) along the c-axis.
// Block b owns inner-offset range p in [60b, 60b+60); iterates 4 slabs (i,chunk),
// each slab = 3 c3-outputs of 64 virtual-k (60 real + 4 pad) = 192 vk; total vK=768.
__global__ __launch_bounds__(512, 2) void gemm_kernel(
    const float* __restrict__ x,
    const float* __restrict__ rw, const float* __restrict__ sw, const float* __restrict__ cw,
    const float* __restrict__ W,
    const float* __restrict__ Rr, const float* __restrict__ Rs, const float* __restrict__ Rc,
    float* __restrict__ P)
{
    __shared__ unsigned short lds_a[256 * PA];      // 100352 B, bf16 feats [n][vk]
    __shared__ unsigned int   lds_b[2][16 * 256];   // 2 x 16KB: packed bf16 pairs [vk2][d]

    const int tid = threadIdx.x;
    const int blk = blockIdx.x;
    const int p0 = blk * 60;

    // ---- Rtot = (R_rotate*rw) @ (R_shear*sw) @ (R_scale*cw), row-major [c][d] ----
    float Ar[9], Br[9], Cr[9], T1[9], RT[9];
    #pragma unroll
    for (int e = 0; e < 9; ++e) {
        Ar[e] = Rr[e] * rw[e];
        Br[e] = Rs[e] * sw[e];
        Cr[e] = Rc[e] * cw[e];
    }
    #pragma unroll
    for (int r = 0; r < 3; ++r)
        #pragma unroll
        for (int c = 0; c < 3; ++c)
            T1[r*3+c] = Ar[r*3+0]*Br[0*3+c] + Ar[r*3+1]*Br[1*3+c] + Ar[r*3+2]*Br[2*3+c];
    #pragma unroll
    for (int r = 0; r < 3; ++r)
        #pragma unroll
        for (int c = 0; c < 3; ++c)
            RT[r*3+c] = T1[r*3+0]*Cr[0*3+c] + T1[r*3+1]*Cr[1*3+c] + T1[r*3+2]*Cr[2*3+c];

    // ---- zero A pads once (cols c3*64+60..63 per row); B pads are zeroed inline ----
    if (tid < 256) {
        bf16x4 zz = (bf16x4)0;
        #pragma unroll
        for (int c3 = 0; c3 < 3; ++c3)
            *((bf16x4*)&lds_a[tid*PA + c3*64 + 60]) = zz;   // byte addr % 8 == 0
    }

    const int w  = tid >> 6, l = tid & 63;
    const int lm = l & 31,  lh = l >> 5;
    const int m0 = (w >> 1) * 64;     // 4 wave-rows
    const int d0 = (w & 1) * 128;     // 2 wave-cols

    f32x16 acc[2][4];
    #pragma unroll
    for (int fm = 0; fm < 2; ++fm)
        #pragma unroll
        for (int fd = 0; fd < 4; ++fd)
            acc[fm][fd] = (f32x16)0.0f;

    for (int s = 0; s < 4; ++s) {
        const int i = s >> 1, chunk = s & 1;
        // element offset of (n=0, c'=0, pl=0) in both x and W-row space:
        const long kbase = (long)i * 90000 + (long)chunk * 45000 + p0;
        const float* xs = x + kbase;

        // ---- issue W loads for sub-tile 0 (overlaps A staging) ----
        f32x2 L0[4], L1[4];
        int bd[4], bvk2[4];
        #pragma unroll
        for (int jj = 0; jj < 4; ++jj) {
            int item = jj*512 + tid;
            int vk2l = item >> 7, dp = item & 127;
            int vk = vk2l*2;               // sub-tile 0
            int c3 = vk >> 6, pl = vk & 63;
            bd[jj] = dp*2; bvk2[jj] = vk2l;
            L0[jj] = (f32x2){0.f,0.f}; L1[jj] = (f32x2){0.f,0.f};
            if (pl < 60) {
                const float* wr = W + (kbase + (long)c3*15000 + pl)*256 + dp*2;
                L0[jj] = *(const f32x2*)wr;
                L1[jj] = *(const f32x2*)(wr + 256);
            }
        }

        // ---- A stage: read x once, emit all 3 transformed c-outputs as bf16 ----
        #pragma unroll 6
        for (int j = 0; j < 30; ++j) {
            int q = j*512 + tid;                         // 15360 (n,pl) pairs
            int n = (int)(((unsigned)q * 34953u) >> 21); // q/60 (exact for q<15360)
            int pl = q - n*60;
            const float* px = xs + (long)n*180000 + pl;
            float x0 = px[0], x1 = px[15000], x2 = px[30000];
            float f0 = x0*RT[0] + x1*RT[3] + x2*RT[6];
            float f1 = x0*RT[1] + x1*RT[4] + x2*RT[7];
            float f2 = x0*RT[2] + x1*RT[5] + x2*RT[8];
            int a = n*PA + pl;
            lds_a[a      ] = f2bf(f0);
            lds_a[a +  64] = f2bf(f1);
            lds_a[a + 128] = f2bf(f2);
        }

        // ---- pack + write B sub-tile 0 ----
        #pragma unroll
        for (int jj = 0; jj < 4; ++jj) {
            unsigned int lo = (unsigned int)f2bf(L0[jj].x) | ((unsigned int)f2bf(L1[jj].x) << 16);
            unsigned int hi = (unsigned int)f2bf(L0[jj].y) | ((unsigned int)f2bf(L1[jj].y) << 16);
            unsigned int* pb = &lds_b[0][bvk2[jj]*256 + bd[jj]];
            pb[0] = lo; pb[1] = hi;
        }
        __syncthreads();

        // ---- 6 sub-steps of 32 vk, B double-buffered ----
        for (int t = 0; t < 6; ++t) {
            f32x2 M0[4], M1[4];
            int cd[4], cvk2[4];
            const bool have = (t < 5);
            if (have) {
                #pragma unroll
                for (int jj = 0; jj < 4; ++jj) {
                    int item = jj*512 + tid;
                    int vk2l = item >> 7, dp = item & 127;
                    int vk = (t+1)*32 + vk2l*2;
                    int c3 = vk >> 6, pl = vk & 63;
                    cd[jj] = dp*2; cvk2[jj] = vk2l;
                    M0[jj] = (f32x2){0.f,0.f}; M1[jj] = (f32x2){0.f,0.f};
                    if (pl < 60) {
                        const float* wr = W + (kbase + (long)c3*15000 + pl)*256 + dp*2;
                        M0[jj] = *(const f32x2*)wr;
                        M1[jj] = *(const f32x2*)(wr + 256);
                    }
                }
            }

            const unsigned int* bbuf = lds_b[t & 1];
            #pragma unroll
            for (int kk = 0; kk < 2; ++kk) {
                int vk0 = t*32 + kk*16;
                int kb = vk0 + lh*8;
                bf16x8 af[2];
                #pragma unroll
                for (int fm = 0; fm < 2; ++fm) {
                    const unsigned short* pa = &lds_a[(m0 + fm*32 + lm)*PA + kb];
                    bf16x4 alo = *(const bf16x4*)pa;         // ds_read_b64 (8B-aligned)
                    bf16x4 ahi = *(const bf16x4*)(pa + 4);
                    af[fm] = __builtin_shufflevector(alo, ahi, 0,1,2,3,4,5,6,7);
                }
                #pragma unroll
                for (int fd = 0; fd < 4; ++fd) {
                    int db = d0 + fd*32 + lm;
                    int v2 = kk*8 + lh*4;
                    u32x4 bw = { bbuf[(v2+0)*256 + db], bbuf[(v2+1)*256 + db],
                                 bbuf[(v2+2)*256 + db], bbuf[(v2+3)*256 + db] };
                    bf16x8 bfv = __builtin_bit_cast(bf16x8, bw);
                    #pragma unroll
                    for (int fm = 0; fm < 2; ++fm)
                        acc[fm][fd] = __builtin_amdgcn_mfma_f32_32x32x16_bf16(af[fm], bfv, acc[fm][fd], 0, 0, 0);
                }
            }

            if (have) {
                unsigned int* nb = &lds_b[(t+1) & 1][0];
                #pragma unroll
                for (int jj = 0; jj < 4; ++jj) {
                    unsigned int lo = (unsigned int)f2bf(M0[jj].x) | ((unsigned int)f2bf(M1[jj].x) << 16);
                    unsigned int hi = (unsigned int)f2bf(M0[jj].y) | ((unsigned int)f2bf(M1[jj].y) << 16);
                    unsigned int* pb = &nb[cvk2[jj]*256 + cd[jj]];
                    pb[0] = lo; pb[1] = hi;
                }
            }
            __syncthreads();
        }
    }

    // ---- write fp32 partial C tile ----
    float* Pb = P + (size_t)blk * 65536;
    #pragma unroll
    for (int fm = 0; fm < 2; ++fm)
        #pragma unroll
        for (int fd = 0; fd < 4; ++fd)
            #pragma unroll
            for (int r = 0; r < 16; ++r) {
                int row = m0 + fm*32 + (r & 3) + 8*(r >> 2) + 4*lh;
                int col = d0 + fd*32 + lm;
                Pb[row*256 + col] = acc[fm][fd][r];
            }
}

// Sum 250 partials + bias, write z twice to out, write zhat (row-normalized) to Z.
__global__ __launch_bounds__(1024) void reduce_kernel(
    const float* __restrict__ P, const float* __restrict__ bias,
    float* __restrict__ out, float* __restrict__ Z)
{
    __shared__ float sred[4][256];
    __shared__ float wsum[16];
    const int n = blockIdx.x;
    const int tid = threadIdx.x;
    const int sg = tid >> 8, d = tid & 255;

    const float* p = P + (size_t)n*256 + d;
    float z = 0.f;
    #pragma unroll 8
    for (int s = sg; s < 250; s += 4) z += p[(size_t)s * 65536];
    sred[sg][d] = z;
    __syncthreads();

    float zf = 0.f;
    if (sg == 0) zf = sred[0][d] + sred[1][d] + sred[2][d] + sred[3][d] + bias[d];
    float sq = zf * zf;
    #pragma unroll
    for (int off = 32; off > 0; off >>= 1) sq += __shfl_down(sq, off, 64);
    if ((tid & 63) == 0) wsum[tid >> 6] = sq;
    __syncthreads();
    if (sg == 0) {
        float tot = wsum[0] + wsum[1] + wsum[2] + wsum[3];  // waves 0..3 hold sg==0
        float inv = rsqrtf(tot);
        out[1 + n*256 + d]         = zf;
        out[1 + 65536 + n*256 + d] = zf;
        Z[n*256 + d] = zf * inv;
    }
}

// loss = 2 - (2/255)*(||S||^2/256 - 1), S = sum_n zhat_n
__global__ __launch_bounds__(1024) void loss_kernel(const float* __restrict__ Z, float* __restrict__ out)
{
    __shared__ float sp[4][256];
    __shared__ float w4[16];
    const int tid = threadIdx.x;
    const int g = tid >> 8, d = tid & 255;
    float S = 0.f;
    #pragma unroll 8
    for (int n = g*64; n < g*64 + 64; ++n) S += Z[n*256 + d];
    sp[g][d] = S;
    __syncthreads();
    float v = 0.f;
    if (g == 0) {
        S = sp[0][d] + sp[1][d] + sp[2][d] + sp[3][d];
        v = S * S;
    }
    #pragma unroll
    for (int off = 32; off > 0; off >>= 1) v += __shfl_down(v, off, 64);
    if ((tid & 63) == 0) w4[tid >> 6] = v;
    __syncthreads();
    if (tid == 0) {
        float tot = w4[0] + w4[1] + w4[2] + w4[3];
        out[0] = 2.0f - (2.0f / 255.0f) * (tot * (1.0f / 256.0f) - 1.0f);
    }
}

extern "C" void kernel_launch(void* const* d_in, const int* in_sizes, int n_in,
                              void* d_out, int out_size, void* d_ws, size_t ws_size,
                              hipStream_t stream)
{
    (void)in_sizes; (void)n_in; (void)out_size; (void)ws_size;
    const float* x  = (const float*)d_in[0];
    const float* rw = (const float*)d_in[1];
    const float* sw = (const float*)d_in[2];
    const float* cw = (const float*)d_in[3];
    const float* W  = (const float*)d_in[4];
    const float* bb = (const float*)d_in[5];
    const float* Rr = (const float*)d_in[6];
    const float* Rs = (const float*)d_in[7];
    const float* Rc = (const float*)d_in[8];
    float* out = (float*)d_out;
    float* P = (float*)d_ws;                        // 250 * 65536 fp32 partials
    float* Z = P + (size_t)250 * 65536;             // 65536 fp32 zhat

    gemm_kernel<<<250, 512, 0, stream>>>(x, rw, sw, cw, W, Rr, Rs, Rc, P);
    reduce_kernel<<<256, 1024, 0, stream>>>(P, bb, out, Z);
    loss_kernel<<<1, 1024, 0, stream>>>(Z, out);
}